// Round 7
// baseline (489.506 us; speedup 1.0000x reference)
//
#include <hip/hip_runtime.h>
#include <hip/hip_bf16.h>

#define B_  4096
#define T_  255
#define V_  32000
#define E_  64
#define H_  64
#define D1_ 32

#define NCT           2000   // V/16 col-tiles
#define NCHUNK        10
#define CT_PER_CHUNK  200    // NCT / NCHUNK
#define CT_PER_WAVE   50     // CT_PER_CHUNK / 4 waves

typedef __attribute__((ext_vector_type(8))) short bf16x8;   // 8 bf16 = 4 VGPR
typedef __attribute__((ext_vector_type(4))) float f32x4;

__device__ __forceinline__ ushort f2bf(float f) {
    __hip_bfloat16 h = __float2bfloat16(f);   // RNE
    return *reinterpret_cast<ushort*>(&h);
}
__device__ __forceinline__ float fast_sigmoid(float x) {
    return __builtin_amdgcn_rcpf(1.f + __expf(-x));
}
__device__ __forceinline__ float fast_tanh(float x) {
    return 1.f - 2.f * __builtin_amdgcn_rcpf(1.f + __expf(2.f * x));
}

// Swizzled byte offset in a [16 rows][64 bf16] (128 B/row) h-tile.
__device__ __forceinline__ int hswz(int row, int colb) {
    return row * 128 + (colb ^ ((row & 7) << 4));
}

// ---------------------------------------------------------------------------
// Kernel 0: one-time emb fp32 -> bf16 (gatherable as A-fragments).
// ---------------------------------------------------------------------------
__global__ __launch_bounds__(256)
void emb2bf_kernel(const float* __restrict__ emb, ushort* __restrict__ emb_bf)
{
    int i = blockIdx.x * 256 + threadIdx.x;      // over V*64/8 = 256000
    const float4 a = ((const float4*)emb)[i * 2];
    const float4 b = ((const float4*)emb)[i * 2 + 1];
    ushort t[8] = { f2bf(a.x), f2bf(a.y), f2bf(a.z), f2bf(a.w),
                    f2bf(b.x), f2bf(b.y), f2bf(b.z), f2bf(b.w) };
    *(ushort4*)(&emb_bf[i * 8])     = *(ushort4*)(&t[0]);
    *(ushort4*)(&emb_bf[i * 8 + 4]) = *(ushort4*)(&t[4]);
}

// ===========================================================================
// lstm_v5: R5 kernel UNCHANGED — launched only to calibrate timing
// (lstm_new = total_R6 - total_R5). Its h output is overwritten by the
// new kernel below, which owns correctness.
// ===========================================================================
__global__ __launch_bounds__(256)
void lstm_mfma_v5(const int* __restrict__ idx,
                  const ushort* __restrict__ emb_bf,
                  const float* __restrict__ Wx,
                  const float* __restrict__ Wh,
                  const float* __restrict__ b,
                  float* __restrict__ h_out)
{
    __shared__ __align__(16) char hbuf[2][2048];
    __shared__ int idxs[16 * 257];

    const int tid  = threadIdx.x;
    const int lane = tid & 63;
    const int w    = tid >> 6;
    const int r0   = blockIdx.x * 16;
    const int lrow = lane & 15;
    const int lhi  = lane >> 4;
    const int jcol = w * 16 + lrow;

    bf16x8 bw[16];
    float bias[4];
    #pragma unroll
    for (int g = 0; g < 4; ++g) {
        const int col = g * 64 + jcol;
        bias[g] = b[col];
        #pragma unroll
        for (int s = 0; s < 4; ++s) {
            bf16x8 f;
            #pragma unroll
            for (int i = 0; i < 8; ++i) {
                int k = s * 32 + lhi * 8 + i;
                float v = (k < 64) ? Wx[k * 256 + col] : Wh[(k - 64) * 256 + col];
                f[i] = (short)f2bf(v);
            }
            bw[g * 4 + s] = f;
        }
    }
    {
        const int row = tid >> 4, tc = tid & 15;
        #pragma unroll
        for (int k = 0; k < 16; ++k) {
            int t = k * 16 + tc;
            if (t < T_) idxs[row * 257 + t] = idx[(r0 + row) * T_ + t];
        }
        ((float2*)hbuf[0])[tid] = make_float2(0.f, 0.f);
    }
    __syncthreads();

    bf16x8 xc0, xc1, xn0, xn1;
    {
        int iv = idxs[lrow * 257 + 0];
        xc0 = *(const bf16x8*)(emb_bf + iv * 64 + lhi * 8);
        xc1 = *(const bf16x8*)(emb_bf + iv * 64 + 32 + lhi * 8);
        iv = idxs[lrow * 257 + 1];
        xn0 = *(const bf16x8*)(emb_bf + iv * 64 + lhi * 8);
        xn1 = *(const bf16x8*)(emb_bf + iv * 64 + 32 + lhi * 8);
    }

    float cst[4]  = {0.f, 0.f, 0.f, 0.f};
    float hreg[4] = {0.f, 0.f, 0.f, 0.f};

    for (int t = 0; t < T_; ++t) {
        const int p = t & 1;
        bf16x8 ah2 = *(const bf16x8*)(&hbuf[p][hswz(lrow, lhi * 16)]);
        bf16x8 ah3 = *(const bf16x8*)(&hbuf[p][hswz(lrow, 64 + lhi * 16)]);

        f32x4 z[4];
        #pragma unroll
        for (int g = 0; g < 4; ++g) z[g] = (f32x4){bias[g], bias[g], bias[g], bias[g]};
        #pragma unroll
        for (int g = 0; g < 4; ++g) z[g] = __builtin_amdgcn_mfma_f32_16x16x32_bf16(xc0, bw[g * 4 + 0], z[g], 0, 0, 0);
        #pragma unroll
        for (int g = 0; g < 4; ++g) z[g] = __builtin_amdgcn_mfma_f32_16x16x32_bf16(xc1, bw[g * 4 + 1], z[g], 0, 0, 0);
        #pragma unroll
        for (int g = 0; g < 4; ++g) z[g] = __builtin_amdgcn_mfma_f32_16x16x32_bf16(ah2, bw[g * 4 + 2], z[g], 0, 0, 0);
        #pragma unroll
        for (int g = 0; g < 4; ++g) z[g] = __builtin_amdgcn_mfma_f32_16x16x32_bf16(ah3, bw[g * 4 + 3], z[g], 0, 0, 0);

        xc0 = xn0; xc1 = xn1;
        if (t + 2 < T_) {
            int iv = idxs[lrow * 257 + (t + 2)];
            xn0 = *(const bf16x8*)(emb_bf + iv * 64 + lhi * 8);
            xn1 = *(const bf16x8*)(emb_bf + iv * 64 + 32 + lhi * 8);
        }

        #pragma unroll
        for (int r = 0; r < 4; ++r) {
            float cn = fast_sigmoid(z[1][r]) * cst[r]
                     + fast_sigmoid(z[0][r]) * fast_tanh(z[2][r]);
            cst[r] = cn;
            float hn = fast_sigmoid(z[3][r]) * fast_tanh(cn);
            hreg[r] = hn;
            const int row = lhi * 4 + r;
            *(ushort*)(&hbuf[p ^ 1][hswz(row, 2 * jcol)]) = f2bf(hn);
        }
        asm volatile("s_waitcnt lgkmcnt(0)\n\ts_barrier" ::: "memory");
    }

    #pragma unroll
    for (int r = 0; r < 4; ++r)
        h_out[(r0 + lhi * 4 + r) * H_ + jcol] = hreg[r];
}

// ===========================================================================
// lstm_mfma_kernel (NEW): dual-slot x pipeline, unrolled by 2, NO register
// rotation — even steps use/reload {xe0,xe1}, odd steps {xo0,xo1}. Reload
// is issued right after the MFMAs consume the regs (WAR-safe: operands are
// sampled at issue), giving a true 2-step load->use distance across 2 raw
// barriers. The RAW vmcnt wait before step t's MFMA leaves step t-1's loads
// in flight (vmcnt(2), never 0).
// ===========================================================================
__global__ __launch_bounds__(256)
void lstm_mfma_kernel(const int* __restrict__ idx,
                      const ushort* __restrict__ emb_bf,
                      const float* __restrict__ Wx,
                      const float* __restrict__ Wh,
                      const float* __restrict__ b,
                      float* __restrict__ h_out)
{
    __shared__ __align__(16) char hbuf[2][2048];   // [buf][16 rows][64 bf16]
    __shared__ int idxs[16 * 257];                 // [row][t], stride 257

    const int tid  = threadIdx.x;
    const int lane = tid & 63;
    const int w    = tid >> 6;          // unit group
    const int r0   = blockIdx.x * 16;
    const int lrow = lane & 15;
    const int lhi  = lane >> 4;
    const int jcol = w * 16 + lrow;

    // persistent B fragments: 4 gates x 4 K-slices
    bf16x8 bw[16];
    float bias[4];
    #pragma unroll
    for (int g = 0; g < 4; ++g) {
        const int col = g * 64 + jcol;
        bias[g] = b[col];
        #pragma unroll
        for (int s = 0; s < 4; ++s) {
            bf16x8 f;
            #pragma unroll
            for (int i = 0; i < 8; ++i) {
                int k = s * 32 + lhi * 8 + i;
                float v = (k < 64) ? Wx[k * 256 + col] : Wh[(k - 64) * 256 + col];
                f[i] = (short)f2bf(v);
            }
            bw[g * 4 + s] = f;
        }
    }

    {
        const int row = tid >> 4, tc = tid & 15;
        #pragma unroll
        for (int k = 0; k < 16; ++k) {
            int t = k * 16 + tc;
            if (t < T_) idxs[row * 257 + t] = idx[(r0 + row) * T_ + t];
        }
        ((float2*)hbuf[0])[tid] = make_float2(0.f, 0.f);
    }
    __syncthreads();

    // dual-slot pipeline registers
    bf16x8 xe0, xe1, xo0, xo1;
    {
        int iv = idxs[lrow * 257 + 0];
        xe0 = *(const bf16x8*)(emb_bf + iv * 64 + lhi * 8);
        xe1 = *(const bf16x8*)(emb_bf + iv * 64 + 32 + lhi * 8);
        iv = idxs[lrow * 257 + 1];
        xo0 = *(const bf16x8*)(emb_bf + iv * 64 + lhi * 8);
        xo1 = *(const bf16x8*)(emb_bf + iv * 64 + 32 + lhi * 8);
    }

    float cst[4]  = {0.f, 0.f, 0.f, 0.f};
    float hreg[4] = {0.f, 0.f, 0.f, 0.f};

    auto do_step = [&](int t, bf16x8& x0, bf16x8& x1) {
        const int p = t & 1;
        bf16x8 ah2 = *(const bf16x8*)(&hbuf[p][hswz(lrow, lhi * 16)]);
        bf16x8 ah3 = *(const bf16x8*)(&hbuf[p][hswz(lrow, 64 + lhi * 16)]);

        f32x4 z[4];
        #pragma unroll
        for (int g = 0; g < 4; ++g) z[g] = (f32x4){bias[g], bias[g], bias[g], bias[g]};
        #pragma unroll
        for (int g = 0; g < 4; ++g) z[g] = __builtin_amdgcn_mfma_f32_16x16x32_bf16(x0, bw[g * 4 + 0], z[g], 0, 0, 0);
        #pragma unroll
        for (int g = 0; g < 4; ++g) z[g] = __builtin_amdgcn_mfma_f32_16x16x32_bf16(x1, bw[g * 4 + 1], z[g], 0, 0, 0);
        #pragma unroll
        for (int g = 0; g < 4; ++g) z[g] = __builtin_amdgcn_mfma_f32_16x16x32_bf16(ah2, bw[g * 4 + 2], z[g], 0, 0, 0);
        #pragma unroll
        for (int g = 0; g < 4; ++g) z[g] = __builtin_amdgcn_mfma_f32_16x16x32_bf16(ah3, bw[g * 4 + 3], z[g], 0, 0, 0);

        // reload THIS slot for t+2 (consumed 2 steps / 2 barriers later)
        if (t + 2 < T_) {
            int iv = idxs[lrow * 257 + (t + 2)];
            x0 = *(const bf16x8*)(emb_bf + iv * 64 + lhi * 8);
            x1 = *(const bf16x8*)(emb_bf + iv * 64 + 32 + lhi * 8);
        }

        #pragma unroll
        for (int r = 0; r < 4; ++r) {
            float cn = fast_sigmoid(z[1][r]) * cst[r]
                     + fast_sigmoid(z[0][r]) * fast_tanh(z[2][r]);
            cst[r] = cn;
            float hn = fast_sigmoid(z[3][r]) * fast_tanh(cn);
            hreg[r] = hn;
            const int row = lhi * 4 + r;
            *(ushort*)(&hbuf[p ^ 1][hswz(row, 2 * jcol)]) = f2bf(hn);
        }

        // LDS-only fence + raw barrier (global loads stay in flight)
        asm volatile("s_waitcnt lgkmcnt(0)\n\ts_barrier" ::: "memory");
    };

    for (int t = 0; t + 1 < T_; t += 2) {
        do_step(t,     xe0, xe1);
        do_step(t + 1, xo0, xo1);
    }
    do_step(T_ - 1, xe0, xe1);   // T_=255 odd: tail is an even-slot step

    #pragma unroll
    for (int r = 0; r < 4; ++r)
        h_out[(r0 + lhi * 4 + r) * H_ + jcol] = hreg[r];
}

// ---------------------------------------------------------------------------
// Kernel 2: out32bf = bf16(relu(h @ W1 + b1))   [4096,64]@[64,32]
// ---------------------------------------------------------------------------
__global__ __launch_bounds__(256)
void head1_kernel(const float* __restrict__ h,
                  const float* __restrict__ W1,
                  const float* __restrict__ b1,
                  ushort* __restrict__ out32bf)
{
    int i = blockIdx.x * 256 + threadIdx.x;   // over 4096*32
    int r = i >> 5, d = i & 31;
    float a = b1[d];
    #pragma unroll
    for (int k = 0; k < 64; ++k)
        a = fmaf(h[r * H_ + k], W1[k * D1_ + d], a);
    out32bf[i] = f2bf(fmaxf(a, 0.f));
}

// ---------------------------------------------------------------------------
// Kernel 2b: repack W2 (fp32 row-major [32][V]) -> bf16 B-frag-linear.
// ---------------------------------------------------------------------------
__global__ __launch_bounds__(256)
void repack_w2_kernel(const float* __restrict__ W2, ushort* __restrict__ w2p)
{
    int t = blockIdx.x * 256 + threadIdx.x;   // over NCT*64
    if (t >= NCT * 64) return;
    int ct = t >> 6, l = t & 63;
    int kbase = (l >> 4) * 8, c = ct * 16 + (l & 15);
    ushort tmp[8];
    #pragma unroll
    for (int i = 0; i < 8; ++i)
        tmp[i] = f2bf(W2[(kbase + i) * V_ + c]);
    *(ushort4*)(&w2p[t * 8])     = *(ushort4*)(&tmp[0]);
    *(ushort4*)(&w2p[t * 8 + 4]) = *(ushort4*)(&tmp[4]);
}

// ---------------------------------------------------------------------------
// Kernel 3: logits = out32 @ W2 + b2, softmax over V, via MFMA.
// ---------------------------------------------------------------------------
template <int PASS>
__global__ __launch_bounds__(256)
void head2_mfma_kernel(const ushort* __restrict__ out32bf,
                       const ushort* __restrict__ w2p,
                       const float* __restrict__ b2,
                       float* __restrict__ partial,   // [B][NCHUNK]
                       float* __restrict__ out)
{
    __shared__ float red[4][16];
    __shared__ float sinvs[16];

    const int tid  = threadIdx.x;
    const int lane = tid & 63;
    const int w    = tid >> 6;
    const int lrow = lane & 15;
    const int lhi  = lane >> 4;
    const int r0    = blockIdx.x * 16;
    const int chunk = blockIdx.y;

    if (PASS == 2) {
        if (tid < 16) {
            float s = 0.f;
            #pragma unroll
            for (int c = 0; c < NCHUNK; ++c) s += partial[(r0 + tid) * NCHUNK + c];
            sinvs[tid] = 1.f / s;
        }
        __syncthreads();
    }

    const bf16x8 A = *(const bf16x8*)(out32bf + (r0 + lrow) * D1_ + lhi * 8);

    float sacc[4] = {0.f, 0.f, 0.f, 0.f};
    float si[4];
    if (PASS == 2) {
        #pragma unroll
        for (int r = 0; r < 4; ++r) si[r] = sinvs[lhi * 4 + r];
    }

    const int ct0 = chunk * CT_PER_CHUNK + w * CT_PER_WAVE;
    for (int i = 0; i < CT_PER_WAVE; ++i) {
        const int ct = ct0 + i;
        const bf16x8 Bf = *(const bf16x8*)(w2p + ct * 512 + lane * 8);
        f32x4 z = __builtin_amdgcn_mfma_f32_16x16x32_bf16(A, Bf, (f32x4){0.f, 0.f, 0.f, 0.f}, 0, 0, 0);
        const float b2v = b2[ct * 16 + lrow];
        #pragma unroll
        for (int r = 0; r < 4; ++r) {
            float e = __expf(z[r] + b2v);
            if (PASS == 1) sacc[r] += e;
            else out[(size_t)(r0 + lhi * 4 + r) * V_ + ct * 16 + lrow] = e * si[r];
        }
    }

    if (PASS == 1) {
        #pragma unroll
        for (int r = 0; r < 4; ++r) {
            float v = sacc[r];
            #pragma unroll
            for (int off = 1; off < 16; off <<= 1) v += __shfl_xor(v, off, 16);
            if (lrow == 0) red[w][lhi * 4 + r] = v;
        }
        __syncthreads();
        if (tid < 16)
            partial[(r0 + tid) * NCHUNK + chunk] =
                red[0][tid] + red[1][tid] + red[2][tid] + red[3][tid];
    }
}

// ---------------------------------------------------------------------------
extern "C" void kernel_launch(void* const* d_in, const int* in_sizes, int n_in,
                              void* d_out, int out_size, void* d_ws, size_t ws_size,
                              hipStream_t stream)
{
    (void)in_sizes; (void)n_in; (void)out_size; (void)ws_size;

    const int*   idx = (const int*)  d_in[0];
    const float* emb = (const float*)d_in[1];
    const float* Wx  = (const float*)d_in[2];
    const float* Wh  = (const float*)d_in[3];
    const float* bl  = (const float*)d_in[4];
    const float* W1  = (const float*)d_in[5];
    const float* b1  = (const float*)d_in[6];
    const float* W2  = (const float*)d_in[7];
    const float* b2  = (const float*)d_in[8];
    float* out = (float*)d_out;

    float*  ws      = (float*)d_ws;
    float*  h       = ws;                                    // 262144 f32
    ushort* out32bf = (ushort*)(ws + 262144);                // 131072 us
    ushort* w2p     = (ushort*)(ws + 262144 + 65536);        // 1024000 us
    float*  part    = ws + 262144 + 65536 + 512000;          // 40960 f32
    ushort* emb_bf  = (ushort*)(ws + 262144 + 65536 + 512000 + 40960);  // 2048000 us

    emb2bf_kernel<<<(V_ * E_ / 8) / 256, 256, 0, stream>>>(emb, emb_bf);
    repack_w2_kernel<<<(NCT * 64 + 255) / 256, 256, 0, stream>>>(W2, w2p);

    // calibration launch (R5 kernel, unchanged): lstm_new = total_R6 - total_R5
    lstm_mfma_v5<<<256, 256, 0, stream>>>(idx, emb_bf, Wx, Wh, bl, h);
    // correctness-owning launch (new kernel overwrites h)
    lstm_mfma_kernel<<<256, 256, 0, stream>>>(idx, emb_bf, Wx, Wh, bl, h);

    head1_kernel<<<(B_ * D1_) / 256, 256, 0, stream>>>(h, W1, b1, out32bf);

    dim3 g3(B_ / 16, NCHUNK);
    head2_mfma_kernel<1><<<g3, 256, 0, stream>>>(out32bf, w2p, b2, part, out);
    head2_mfma_kernel<2><<<g3, 256, 0, stream>>>(out32bf, w2p, b2, part, out);
}

// Round 8
// 360.147 us; speedup vs baseline: 1.3592x; 1.3592x over previous
//
#include <hip/hip_runtime.h>
#include <hip/hip_bf16.h>

#define B_  4096
#define T_  255
#define V_  32000
#define E_  64
#define H_  64
#define D1_ 32

#define NCT           2000   // V/16 col-tiles
#define NCHUNK        10
#define CT_PER_CHUNK  200    // NCT / NCHUNK
#define CT_PER_WAVE   50     // CT_PER_CHUNK / 4 waves

typedef __attribute__((ext_vector_type(8))) short bf16x8;   // 8 bf16 = 4 VGPR
typedef __attribute__((ext_vector_type(4))) float f32x4;

__device__ __forceinline__ ushort f2bf(float f) {
    __hip_bfloat16 h = __float2bfloat16(f);   // RNE
    return *reinterpret_cast<ushort*>(&h);
}
__device__ __forceinline__ float fast_sigmoid(float x) {
    return __builtin_amdgcn_rcpf(1.f + __expf(-x));
}
__device__ __forceinline__ float fast_tanh(float x) {
    return 1.f - 2.f * __builtin_amdgcn_rcpf(1.f + __expf(2.f * x));
}

// Swizzled byte offset in a [16 rows][64 bf16] (128 B/row) h-tile.
__device__ __forceinline__ int hswz(int row, int colb) {
    return row * 128 + (colb ^ ((row & 7) << 4));
}

// ---------------------------------------------------------------------------
// Kernel 0 (merged): blocks [0,1000): emb fp32->bf16 ; [1000,1500): W2 repack.
// ---------------------------------------------------------------------------
__global__ __launch_bounds__(256)
void prep_kernel(const float* __restrict__ emb, ushort* __restrict__ emb_bf,
                 const float* __restrict__ W2,  ushort* __restrict__ w2p)
{
    if (blockIdx.x < 1000) {
        int i = blockIdx.x * 256 + threadIdx.x;      // over V*64/8 = 256000
        const float4 a = ((const float4*)emb)[i * 2];
        const float4 b = ((const float4*)emb)[i * 2 + 1];
        ushort t[8] = { f2bf(a.x), f2bf(a.y), f2bf(a.z), f2bf(a.w),
                        f2bf(b.x), f2bf(b.y), f2bf(b.z), f2bf(b.w) };
        *(ushort4*)(&emb_bf[i * 8])     = *(ushort4*)(&t[0]);
        *(ushort4*)(&emb_bf[i * 8 + 4]) = *(ushort4*)(&t[4]);
    } else {
        int t = (blockIdx.x - 1000) * 256 + threadIdx.x;   // over NCT*64
        if (t >= NCT * 64) return;
        int ct = t >> 6, l = t & 63;
        int kbase = (l >> 4) * 8, c = ct * 16 + (l & 15);
        ushort tmp[8];
        #pragma unroll
        for (int i = 0; i < 8; ++i)
            tmp[i] = f2bf(W2[(kbase + i) * V_ + c]);
        *(ushort4*)(&w2p[t * 8])     = *(ushort4*)(&tmp[0]);
        *(ushort4*)(&w2p[t * 8 + 4]) = *(ushort4*)(&tmp[4]);
    }
}

// ===========================================================================
// LSTM, bf16 MFMA, zx-precompute: zx(t) = bias + x(t)@Wx is computed 2 steps
// ahead (8 MFMAs independent of the recurrence, overlapping VALU/activation),
// so the per-step serial chain is only: ds_read h -> 2-deep MFMA ->
// activation -> ds_write -> lgkm-only barrier. x gathers stay 2 steps deep
// (even/odd slots, no register rotation -> loads in flight across barriers).
// ===========================================================================
__global__ __launch_bounds__(256)
void lstm_mfma_kernel(const int* __restrict__ idx,
                      const ushort* __restrict__ emb_bf,
                      const float* __restrict__ Wx,
                      const float* __restrict__ Wh,
                      const float* __restrict__ b,
                      float* __restrict__ h_out)
{
    __shared__ __align__(16) char hbuf[2][2048];   // [buf][16 rows][64 bf16]
    __shared__ int idxs[16 * 257];                 // [row][t], stride 257

    const int tid  = threadIdx.x;
    const int lane = tid & 63;
    const int w    = tid >> 6;          // unit group
    const int r0   = blockIdx.x * 16;
    const int lrow = lane & 15;
    const int lhi  = lane >> 4;
    const int jcol = w * 16 + lrow;

    // persistent B fragments: 4 gates x 4 K-slices (s=0,1: Wx ; s=2,3: Wh)
    bf16x8 bw[16];
    float bias[4];
    #pragma unroll
    for (int g = 0; g < 4; ++g) {
        const int col = g * 64 + jcol;
        bias[g] = b[col];
        #pragma unroll
        for (int s = 0; s < 4; ++s) {
            bf16x8 f;
            #pragma unroll
            for (int i = 0; i < 8; ++i) {
                int k = s * 32 + lhi * 8 + i;
                float v = (k < 64) ? Wx[k * 256 + col] : Wh[(k - 64) * 256 + col];
                f[i] = (short)f2bf(v);
            }
            bw[g * 4 + s] = f;
        }
    }

    {
        const int row = tid >> 4, tc = tid & 15;
        #pragma unroll
        for (int k = 0; k < 16; ++k) {
            int t = k * 16 + tc;
            if (t < T_) idxs[row * 257 + t] = idx[(r0 + row) * T_ + t];
        }
        ((float2*)hbuf[0])[tid] = make_float2(0.f, 0.f);
    }
    __syncthreads();

    // ---- prologue: zx(0), zx(1); x(2), x(3) in flight ----
    f32x4 zxe[4], zxo[4];
    bf16x8 xe0, xe1, xo0, xo1;
    {
        int iv = idxs[lrow * 257 + 0];
        bf16x8 a0 = *(const bf16x8*)(emb_bf + iv * 64 + lhi * 8);
        bf16x8 a1 = *(const bf16x8*)(emb_bf + iv * 64 + 32 + lhi * 8);
        #pragma unroll
        for (int g = 0; g < 4; ++g) {
            zxe[g] = (f32x4){bias[g], bias[g], bias[g], bias[g]};
            zxe[g] = __builtin_amdgcn_mfma_f32_16x16x32_bf16(a0, bw[g * 4 + 0], zxe[g], 0, 0, 0);
            zxe[g] = __builtin_amdgcn_mfma_f32_16x16x32_bf16(a1, bw[g * 4 + 1], zxe[g], 0, 0, 0);
        }
        iv = idxs[lrow * 257 + 1];
        a0 = *(const bf16x8*)(emb_bf + iv * 64 + lhi * 8);
        a1 = *(const bf16x8*)(emb_bf + iv * 64 + 32 + lhi * 8);
        #pragma unroll
        for (int g = 0; g < 4; ++g) {
            zxo[g] = (f32x4){bias[g], bias[g], bias[g], bias[g]};
            zxo[g] = __builtin_amdgcn_mfma_f32_16x16x32_bf16(a0, bw[g * 4 + 0], zxo[g], 0, 0, 0);
            zxo[g] = __builtin_amdgcn_mfma_f32_16x16x32_bf16(a1, bw[g * 4 + 1], zxo[g], 0, 0, 0);
        }
        iv = idxs[lrow * 257 + 2];
        xe0 = *(const bf16x8*)(emb_bf + iv * 64 + lhi * 8);
        xe1 = *(const bf16x8*)(emb_bf + iv * 64 + 32 + lhi * 8);
        iv = idxs[lrow * 257 + 3];
        xo0 = *(const bf16x8*)(emb_bf + iv * 64 + lhi * 8);
        xo1 = *(const bf16x8*)(emb_bf + iv * 64 + 32 + lhi * 8);
    }

    float cst[4]  = {0.f, 0.f, 0.f, 0.f};
    float hreg[4] = {0.f, 0.f, 0.f, 0.f};

    // one step; zx = this parity's zx slot (consumed, then recomputed for
    // t+2 from x slot), x slot reloaded for t+4.
    auto do_step = [&](int t, f32x4* zx, bf16x8& x0, bf16x8& x1) {
        const int p = t & 1;
        // serial chain head: h(t-1) fragments
        bf16x8 ah2 = *(const bf16x8*)(&hbuf[p][hswz(lrow, lhi * 16)]);
        bf16x8 ah3 = *(const bf16x8*)(&hbuf[p][hswz(lrow, 64 + lhi * 16)]);

        // z = zx + h @ Wh   (2-deep chain, 4 parallel gates)
        f32x4 z[4];
        #pragma unroll
        for (int g = 0; g < 4; ++g)
            z[g] = __builtin_amdgcn_mfma_f32_16x16x32_bf16(ah2, bw[g * 4 + 2], zx[g], 0, 0, 0);
        #pragma unroll
        for (int g = 0; g < 4; ++g)
            z[g] = __builtin_amdgcn_mfma_f32_16x16x32_bf16(ah3, bw[g * 4 + 3], z[g], 0, 0, 0);

        // recompute this slot's zx for t+2 (x loaded 2 steps ago; these 8
        // MFMAs are off the critical path — they overlap activation VALU)
        if (t + 2 < T_) {
            #pragma unroll
            for (int g = 0; g < 4; ++g) {
                zx[g] = (f32x4){bias[g], bias[g], bias[g], bias[g]};
                zx[g] = __builtin_amdgcn_mfma_f32_16x16x32_bf16(x0, bw[g * 4 + 0], zx[g], 0, 0, 0);
                zx[g] = __builtin_amdgcn_mfma_f32_16x16x32_bf16(x1, bw[g * 4 + 1], zx[g], 0, 0, 0);
            }
        }
        // reload this x slot for t+4 (in flight across 2 barriers)
        if (t + 4 < T_) {
            int iv = idxs[lrow * 257 + (t + 4)];
            x0 = *(const bf16x8*)(emb_bf + iv * 64 + lhi * 8);
            x1 = *(const bf16x8*)(emb_bf + iv * 64 + 32 + lhi * 8);
        }

        // activation (wave-local)
        #pragma unroll
        for (int r = 0; r < 4; ++r) {
            float cn = fast_sigmoid(z[1][r]) * cst[r]
                     + fast_sigmoid(z[0][r]) * fast_tanh(z[2][r]);
            cst[r] = cn;
            float hn = fast_sigmoid(z[3][r]) * fast_tanh(cn);
            hreg[r] = hn;
            const int row = lhi * 4 + r;
            *(ushort*)(&hbuf[p ^ 1][hswz(row, 2 * jcol)]) = f2bf(hn);
        }

        // LDS-only fence + raw barrier (global loads stay in flight)
        asm volatile("s_waitcnt lgkmcnt(0)\n\ts_barrier" ::: "memory");
    };

    for (int t = 0; t + 1 < T_; t += 2) {
        do_step(t,     zxe, xe0, xe1);
        do_step(t + 1, zxo, xo0, xo1);
    }
    do_step(T_ - 1, zxe, xe0, xe1);   // T_=255 odd: tail is an even-slot step

    #pragma unroll
    for (int r = 0; r < 4; ++r)
        h_out[(r0 + lhi * 4 + r) * H_ + jcol] = hreg[r];
}

// ---------------------------------------------------------------------------
// Kernel 2: out32bf = bf16(relu(h @ W1 + b1))   [4096,64]@[64,32]
// ---------------------------------------------------------------------------
__global__ __launch_bounds__(256)
void head1_kernel(const float* __restrict__ h,
                  const float* __restrict__ W1,
                  const float* __restrict__ b1,
                  ushort* __restrict__ out32bf)
{
    int i = blockIdx.x * 256 + threadIdx.x;   // over 4096*32
    int r = i >> 5, d = i & 31;
    float a = b1[d];
    #pragma unroll
    for (int k = 0; k < 64; ++k)
        a = fmaf(h[r * H_ + k], W1[k * D1_ + d], a);
    out32bf[i] = f2bf(fmaxf(a, 0.f));
}

// ---------------------------------------------------------------------------
// Kernel 3: logits = out32 @ W2 + b2, softmax over V, via MFMA.
// ---------------------------------------------------------------------------
template <int PASS>
__global__ __launch_bounds__(256)
void head2_mfma_kernel(const ushort* __restrict__ out32bf,
                       const ushort* __restrict__ w2p,
                       const float* __restrict__ b2,
                       float* __restrict__ partial,   // [B][NCHUNK]
                       float* __restrict__ out)
{
    __shared__ float red[4][16];
    __shared__ float sinvs[16];

    const int tid  = threadIdx.x;
    const int lane = tid & 63;
    const int w    = tid >> 6;
    const int lrow = lane & 15;
    const int lhi  = lane >> 4;
    const int r0    = blockIdx.x * 16;
    const int chunk = blockIdx.y;

    if (PASS == 2) {
        if (tid < 16) {
            float s = 0.f;
            #pragma unroll
            for (int c = 0; c < NCHUNK; ++c) s += partial[(r0 + tid) * NCHUNK + c];
            sinvs[tid] = 1.f / s;
        }
        __syncthreads();
    }

    const bf16x8 A = *(const bf16x8*)(out32bf + (r0 + lrow) * D1_ + lhi * 8);

    float sacc[4] = {0.f, 0.f, 0.f, 0.f};
    float si[4];
    if (PASS == 2) {
        #pragma unroll
        for (int r = 0; r < 4; ++r) si[r] = sinvs[lhi * 4 + r];
    }

    const int ct0 = chunk * CT_PER_CHUNK + w * CT_PER_WAVE;
    for (int i = 0; i < CT_PER_WAVE; ++i) {
        const int ct = ct0 + i;
        const bf16x8 Bf = *(const bf16x8*)(w2p + ct * 512 + lane * 8);
        f32x4 z = __builtin_amdgcn_mfma_f32_16x16x32_bf16(A, Bf, (f32x4){0.f, 0.f, 0.f, 0.f}, 0, 0, 0);
        const float b2v = b2[ct * 16 + lrow];
        #pragma unroll
        for (int r = 0; r < 4; ++r) {
            float e = __expf(z[r] + b2v);
            if (PASS == 1) sacc[r] += e;
            else out[(size_t)(r0 + lhi * 4 + r) * V_ + ct * 16 + lrow] = e * si[r];
        }
    }

    if (PASS == 1) {
        #pragma unroll
        for (int r = 0; r < 4; ++r) {
            float v = sacc[r];
            #pragma unroll
            for (int off = 1; off < 16; off <<= 1) v += __shfl_xor(v, off, 16);
            if (lrow == 0) red[w][lhi * 4 + r] = v;
        }
        __syncthreads();
        if (tid < 16)
            partial[(r0 + tid) * NCHUNK + chunk] =
                red[0][tid] + red[1][tid] + red[2][tid] + red[3][tid];
    }
}

// ---------------------------------------------------------------------------
extern "C" void kernel_launch(void* const* d_in, const int* in_sizes, int n_in,
                              void* d_out, int out_size, void* d_ws, size_t ws_size,
                              hipStream_t stream)
{
    (void)in_sizes; (void)n_in; (void)out_size; (void)ws_size;

    const int*   idx = (const int*)  d_in[0];
    const float* emb = (const float*)d_in[1];
    const float* Wx  = (const float*)d_in[2];
    const float* Wh  = (const float*)d_in[3];
    const float* bl  = (const float*)d_in[4];
    const float* W1  = (const float*)d_in[5];
    const float* b1  = (const float*)d_in[6];
    const float* W2  = (const float*)d_in[7];
    const float* b2  = (const float*)d_in[8];
    float* out = (float*)d_out;

    float*  ws      = (float*)d_ws;
    float*  h       = ws;                                    // 262144 f32
    ushort* out32bf = (ushort*)(ws + 262144);                // 131072 us
    ushort* w2p     = (ushort*)(ws + 262144 + 65536);        // 1024000 us
    float*  part    = ws + 262144 + 65536 + 512000;          // 40960 f32
    ushort* emb_bf  = (ushort*)(ws + 262144 + 65536 + 512000 + 40960);  // 2048000 us

    prep_kernel<<<1500, 256, 0, stream>>>(emb, emb_bf, W2, w2p);
    lstm_mfma_kernel<<<256, 256, 0, stream>>>(idx, emb_bf, Wx, Wh, bl, h);
    head1_kernel<<<(B_ * D1_) / 256, 256, 0, stream>>>(h, W1, b1, out32bf);

    dim3 g3(B_ / 16, NCHUNK);
    head2_mfma_kernel<1><<<g3, 256, 0, stream>>>(out32bf, w2p, b2, part, out);
    head2_mfma_kernel<2><<<g3, 256, 0, stream>>>(out32bf, w2p, b2, part, out);
}